// Round 1
// baseline (1776.810 us; speedup 1.0000x reference)
//
#include <hip/hip_runtime.h>
#include <math.h>

static constexpr int DIM = 512;   // input feature dim
static constexpr int H   = 16;    // hidden dim
static constexpr int NC  = 40;    // classes

__device__ __forceinline__ float dot4(float4 a, float4 b) {
    return a.x * b.x + a.y * b.y + a.z * b.z + a.w * b.w;
}
__device__ __forceinline__ float waveMax(float v) {
#pragma unroll
    for (int m = 1; m <= 32; m <<= 1) v = fmaxf(v, __shfl_xor(v, m, 64));
    return v;
}
__device__ __forceinline__ float waveSum(float v) {
#pragma unroll
    for (int m = 1; m <= 32; m <<= 1) v += __shfl_xor(v, m, 64);
    return v;
}

// ---------------- CSR build ----------------
__global__ void k_hist(const int* __restrict__ dst, int* __restrict__ cnt, int E) {
    int stride = gridDim.x * blockDim.x;
    for (int i = blockIdx.x * blockDim.x + threadIdx.x; i < E; i += stride)
        atomicAdd(&cnt[dst[i]], 1);
}

__global__ void k_alloc(int* __restrict__ cnt, int* __restrict__ off,
                        int* __restrict__ cursor, int* __restrict__ srcArr,
                        int* __restrict__ gcur, int N) {
    int n = blockIdx.x * blockDim.x + threadIdx.x;
    if (n >= N) return;
    int d = cnt[n] + 1;                 // +1 self-loop
    int start = atomicAdd(gcur, d);
    off[n] = start;
    cnt[n] = d;
    srcArr[start] = n;                  // place self-loop
    cursor[n] = start + 1;
}

__global__ void k_scatter(const int* __restrict__ src, const int* __restrict__ dst,
                          int* __restrict__ cursor, int* __restrict__ srcArr, int E) {
    int stride = gridDim.x * blockDim.x;
    for (int i = blockIdx.x * blockDim.x + threadIdx.x; i < E; i += stride) {
        int d = dst[i];
        int p = atomicAdd(&cursor[d], 1);
        srcArr[p] = src[i];
    }
}

// ---------------- GEMM: h = relu(x @ W1^T + b1), fused row-normalize ----------------
// quarter-wave per node: lane j in [0,16) computes h[n][j]; writes hn (normalized) + clamped norm
__global__ void __launch_bounds__(256) k_gemm(const float* __restrict__ x,
                                              const float* __restrict__ W1,
                                              const float* __restrict__ b1,
                                              float* __restrict__ hn,
                                              float* __restrict__ nrm, int N) {
    const int tid = threadIdx.x;
    const int j = tid & 15;
    const int n = blockIdx.x * 16 + (tid >> 4);
    if (n >= N) return;
    const float4* __restrict__ xr = reinterpret_cast<const float4*>(x + (size_t)n * DIM);
    const float4* __restrict__ wr = reinterpret_cast<const float4*>(W1 + (size_t)j * DIM);
    float acc = 0.f;
#pragma unroll 8
    for (int k = 0; k < DIM / 4; ++k) {
        acc += dot4(xr[k], wr[k]);
    }
    float v = fmaxf(acc + b1[j], 0.f);
    float s = v * v;
    s += __shfl_xor(s, 1, 64); s += __shfl_xor(s, 2, 64);
    s += __shfl_xor(s, 4, 64); s += __shfl_xor(s, 8, 64);
    float nc = fmaxf(sqrtf(s), 1e-12f);
    hn[(size_t)n * H + j] = v / nc;
    if (j == 0) nrm[n] = nc;
}

// ---------------- AGNN propagation ----------------
// wave per node. Softmax over in-edges of cosine-sim*beta, then out = sum_e w_e * h[src_e]
// h[src] reconstructed as hn[src]*nrm[src]. Fast path deg<=128 keeps gathered rows in regs.
template <bool WRITE_HN, bool FIXED_BETA>
__global__ void __launch_bounds__(256) k_prop(
    const float* __restrict__ hn_in, const float* __restrict__ nrm_in,
    float* __restrict__ h_out, float* __restrict__ hn_out, float* __restrict__ nrm_out,
    const float* __restrict__ beta_ptr,
    const int* __restrict__ off, const int* __restrict__ cnt,
    const int* __restrict__ srcArr, int N) {
    const int lane = threadIdx.x & 63;
    const int n = blockIdx.x * 4 + (threadIdx.x >> 6);
    if (n >= N) return;
    const float beta = FIXED_BETA ? 1.0f : beta_ptr[0];
    const int start = off[n];
    const int c = cnt[n];
    const float4* __restrict__ hv = reinterpret_cast<const float4*>(hn_in);
    const size_t nb = (size_t)n * (H / 4);
    const float4 d0 = hv[nb + 0], d1 = hv[nb + 1], d2 = hv[nb + 2], d3 = hv[nb + 3];

    float acc[H];
#pragma unroll
    for (int i = 0; i < H; ++i) acc[i] = 0.f;
    float denom = 0.f;

    if (c <= 128) {
        const bool act1 = lane < c;
        const bool act2 = 64 + lane < c;
        int s1 = 0, s2 = 0;
        float4 a0 = {0,0,0,0}, a1 = {0,0,0,0}, a2 = {0,0,0,0}, a3 = {0,0,0,0};
        float4 g0 = {0,0,0,0}, g1 = {0,0,0,0}, g2 = {0,0,0,0}, g3 = {0,0,0,0};
        float al1 = -INFINITY, al2 = -INFINITY;
        if (act1) {
            s1 = srcArr[start + lane];
            const size_t sb = (size_t)s1 * (H / 4);
            a0 = hv[sb + 0]; a1 = hv[sb + 1]; a2 = hv[sb + 2]; a3 = hv[sb + 3];
            al1 = beta * (dot4(a0, d0) + dot4(a1, d1) + dot4(a2, d2) + dot4(a3, d3));
        }
        if (act2) {
            s2 = srcArr[start + 64 + lane];
            const size_t sb = (size_t)s2 * (H / 4);
            g0 = hv[sb + 0]; g1 = hv[sb + 1]; g2 = hv[sb + 2]; g3 = hv[sb + 3];
            al2 = beta * (dot4(g0, d0) + dot4(g1, d1) + dot4(g2, d2) + dot4(g3, d3));
        }
        const float m = waveMax(fmaxf(al1, al2));
        float ex1 = 0.f, ex2 = 0.f, w1 = 0.f, w2 = 0.f;
        if (act1) { ex1 = __expf(al1 - m); w1 = ex1 * nrm_in[s1]; }
        if (act2) { ex2 = __expf(al2 - m); w2 = ex2 * nrm_in[s2]; }
        denom = ex1 + ex2;
        acc[0]  = w1 * a0.x + w2 * g0.x;  acc[1]  = w1 * a0.y + w2 * g0.y;
        acc[2]  = w1 * a0.z + w2 * g0.z;  acc[3]  = w1 * a0.w + w2 * g0.w;
        acc[4]  = w1 * a1.x + w2 * g1.x;  acc[5]  = w1 * a1.y + w2 * g1.y;
        acc[6]  = w1 * a1.z + w2 * g1.z;  acc[7]  = w1 * a1.w + w2 * g1.w;
        acc[8]  = w1 * a2.x + w2 * g2.x;  acc[9]  = w1 * a2.y + w2 * g2.y;
        acc[10] = w1 * a2.z + w2 * g2.z;  acc[11] = w1 * a2.w + w2 * g2.w;
        acc[12] = w1 * a3.x + w2 * g3.x;  acc[13] = w1 * a3.y + w2 * g3.y;
        acc[14] = w1 * a3.z + w2 * g3.z;  acc[15] = w1 * a3.w + w2 * g3.w;
    } else {
        // rare tail (deg > 128): two passes, recompute alpha in pass 2
        float m = -INFINITY;
        for (int e0 = 0; e0 < c; e0 += 64) {
            if (e0 + lane < c) {
                const int s = srcArr[start + e0 + lane];
                const size_t sb = (size_t)s * (H / 4);
                float4 a0 = hv[sb + 0], a1 = hv[sb + 1], a2 = hv[sb + 2], a3 = hv[sb + 3];
                m = fmaxf(m, beta * (dot4(a0, d0) + dot4(a1, d1) + dot4(a2, d2) + dot4(a3, d3)));
            }
        }
        m = waveMax(m);
        for (int e0 = 0; e0 < c; e0 += 64) {
            if (e0 + lane < c) {
                const int s = srcArr[start + e0 + lane];
                const size_t sb = (size_t)s * (H / 4);
                float4 a0 = hv[sb + 0], a1 = hv[sb + 1], a2 = hv[sb + 2], a3 = hv[sb + 3];
                float al = beta * (dot4(a0, d0) + dot4(a1, d1) + dot4(a2, d2) + dot4(a3, d3));
                float ex = __expf(al - m);
                denom += ex;
                float wv = ex * nrm_in[s];
                acc[0]  += wv * a0.x; acc[1]  += wv * a0.y; acc[2]  += wv * a0.z; acc[3]  += wv * a0.w;
                acc[4]  += wv * a1.x; acc[5]  += wv * a1.y; acc[6]  += wv * a1.z; acc[7]  += wv * a1.w;
                acc[8]  += wv * a2.x; acc[9]  += wv * a2.y; acc[10] += wv * a2.z; acc[11] += wv * a2.w;
                acc[12] += wv * a3.x; acc[13] += wv * a3.y; acc[14] += wv * a3.z; acc[15] += wv * a3.w;
            }
        }
    }
    denom = waveSum(denom);

    // reduce-scatter: 16 features x 64 lanes -> one feature per lane (static indices only)
#pragma unroll
    for (int i = 0; i < 8; ++i) {
        const float snd  = (lane & 1) ? acc[i] : acc[i + 8];
        const float keep = (lane & 1) ? acc[i + 8] : acc[i];
        acc[i] = keep + __shfl_xor(snd, 1, 64);
    }
#pragma unroll
    for (int i = 0; i < 4; ++i) {
        const float snd  = (lane & 2) ? acc[i] : acc[i + 4];
        const float keep = (lane & 2) ? acc[i + 4] : acc[i];
        acc[i] = keep + __shfl_xor(snd, 2, 64);
    }
#pragma unroll
    for (int i = 0; i < 2; ++i) {
        const float snd  = (lane & 4) ? acc[i] : acc[i + 2];
        const float keep = (lane & 4) ? acc[i + 2] : acc[i];
        acc[i] = keep + __shfl_xor(snd, 4, 64);
    }
    {
        const float snd  = (lane & 8) ? acc[0] : acc[1];
        const float keep = (lane & 8) ? acc[1] : acc[0];
        acc[0] = keep + __shfl_xor(snd, 8, 64);
    }
    float v = acc[0];
    v += __shfl_xor(v, 16, 64);
    v += __shfl_xor(v, 32, 64);
    const float o = v / denom;
    const int f = ((lane & 1) << 3) | ((lane & 2) << 1) | ((lane & 4) >> 1) | ((lane & 8) >> 3);

    if (WRITE_HN) {
        float q = o * o;
        q += __shfl_xor(q, 1, 64); q += __shfl_xor(q, 2, 64);
        q += __shfl_xor(q, 4, 64); q += __shfl_xor(q, 8, 64);
        const float nc = fmaxf(sqrtf(q), 1e-12f);
        if (lane < 16) hn_out[(size_t)n * H + f] = o / nc;
        if (lane == 0) nrm_out[n] = nc;
    } else {
        if (lane < 16) h_out[(size_t)n * H + f] = o;
    }
}

// ---------------- output: log_softmax(h3 @ W2^T + b2) ----------------
__global__ void __launch_bounds__(256) k_out(const float* __restrict__ h3,
                                             const float* __restrict__ W2,
                                             const float* __restrict__ b2,
                                             float* __restrict__ out, int N) {
    const int lane = threadIdx.x & 63;
    const int n = blockIdx.x * 4 + (threadIdx.x >> 6);
    if (n >= N) return;
    const float4* __restrict__ hv = reinterpret_cast<const float4*>(h3 + (size_t)n * H);
    const float4 h0 = hv[0], h1 = hv[1], h2 = hv[2], h3v = hv[3];
    float logit = -INFINITY;
    if (lane < NC) {
        const float4* __restrict__ wr = reinterpret_cast<const float4*>(W2 + (size_t)lane * H);
        logit = b2[lane] + dot4(h0, wr[0]) + dot4(h1, wr[1]) + dot4(h2, wr[2]) + dot4(h3v, wr[3]);
    }
    const float m = waveMax(logit);
    const float ex = (lane < NC) ? __expf(logit - m) : 0.f;
    const float s = waveSum(ex);
    if (lane < NC) out[(size_t)n * NC + lane] = logit - m - logf(s);
}

extern "C" void kernel_launch(void* const* d_in, const int* in_sizes, int n_in,
                              void* d_out, int out_size, void* d_ws, size_t ws_size,
                              hipStream_t stream) {
    const float* x     = (const float*)d_in[0];
    const int*   ei    = (const int*)d_in[1];
    const float* W1    = (const float*)d_in[2];
    const float* b1    = (const float*)d_in[3];
    const float* W2    = (const float*)d_in[4];
    const float* b2    = (const float*)d_in[5];
    const float* beta2 = (const float*)d_in[6];
    float* out = (float*)d_out;

    const int N  = in_sizes[0] / DIM;
    const int E  = in_sizes[1] / 2;
    const int E2 = E + N;
    const int* src = ei;
    const int* dst = ei + E;

    char* w = (char*)d_ws;
    auto take = [&](size_t bytes) { char* p = w; w += (bytes + 255) & ~size_t(255); return p; };
    int*   cnt    = (int*)take(((size_t)N + 1) * 4);   // cnt[N] doubles as gcur
    int*   gcur   = cnt + N;
    int*   off    = (int*)take((size_t)N * 4);
    int*   cursor = (int*)take((size_t)N * 4);
    int*   srcArr = (int*)take((size_t)E2 * 4);
    float* hn1    = (float*)take((size_t)N * H * 4);
    float* nr1    = (float*)take((size_t)N * 4);
    float* hn2    = (float*)take((size_t)N * H * 4);
    float* nr2    = (float*)take((size_t)N * 4);
    float* h3     = (float*)take((size_t)N * H * 4);
    (void)ws_size; (void)n_in; (void)out_size;

    hipMemsetAsync(cnt, 0, ((size_t)N + 1) * sizeof(int), stream);
    k_hist<<<2048, 256, 0, stream>>>(dst, cnt, E);
    k_alloc<<<(N + 255) / 256, 256, 0, stream>>>(cnt, off, cursor, srcArr, gcur, N);
    k_scatter<<<2048, 256, 0, stream>>>(src, dst, cursor, srcArr, E);
    k_gemm<<<(N + 15) / 16, 256, 0, stream>>>(x, W1, b1, hn1, nr1, N);
    k_prop<true, true><<<(N + 3) / 4, 256, 0, stream>>>(
        hn1, nr1, nullptr, hn2, nr2, nullptr, off, cnt, srcArr, N);
    k_prop<false, false><<<(N + 3) / 4, 256, 0, stream>>>(
        hn2, nr2, h3, nullptr, nullptr, beta2, off, cnt, srcArr, N);
    k_out<<<(N + 3) / 4, 256, 0, stream>>>(h3, W2, b2, out, N);
}